// Round 1
// baseline (189.674 us; speedup 1.0000x reference)
//
#include <hip/hip_runtime.h>

#define N_ROWS 131072
#define D_COLS 256
#define B_SEG  16
#define ROWS_PER_WAVE 16

// One wave (64 lanes) handles ROWS_PER_WAVE contiguous rows.
// Lane l loads float4 at column 4*l: 64 lanes * 16B = 256 floats = one row.
__global__ __launch_bounds__(256) void umse_main(
    const float* __restrict__ input,
    const float* __restrict__ target,
    const int*   __restrict__ batch,
    float*       __restrict__ acc /* [B_SEG*2]: (loss_pos, loss_neg) pairs */) {

    const int wave = (blockIdx.x * blockDim.x + threadIdx.x) >> 6;
    const int lane = threadIdx.x & 63;
    const long row0 = (long)wave * ROWS_PER_WAVE;

    const float4* __restrict__ in4 = (const float4*)input;
    const float4* __restrict__ tg4 = (const float4*)target;

    float rp = 0.f, rn = 0.f;
    int cur = batch[row0];   // wave-uniform broadcast load

    #pragma unroll 4
    for (int i = 0; i < ROWS_PER_WAVE; ++i) {
        const long r = row0 + i;
        const int b = batch[r];
        if (b != cur) {
            // segment boundary inside this chunk (rare: <=15 waves total hit this)
            float p = rp, n = rn;
            #pragma unroll
            for (int off = 32; off; off >>= 1) {
                p += __shfl_down(p, off);
                n += __shfl_down(n, off);
            }
            if (lane == 0) {
                atomicAdd(&acc[cur * 2 + 0], p);
                atomicAdd(&acc[cur * 2 + 1], n);
            }
            rp = 0.f; rn = 0.f; cur = b;
        }
        const float4 x = in4[r * (D_COLS / 4) + lane];
        const float4 t = tg4[r * (D_COLS / 4) + lane];
        float dxx = x.x - t.x, dxy = x.y - t.y, dxz = x.z - t.z, dxw = x.w - t.w;
        float sxx = x.x + t.x, sxy = x.y + t.y, sxz = x.z + t.z, sxw = x.w + t.w;
        rp += dxx * dxx + dxy * dxy + dxz * dxz + dxw * dxw;
        rn += sxx * sxx + sxy * sxy + sxz * sxz + sxw * sxw;
    }

    // final flush
    #pragma unroll
    for (int off = 32; off; off >>= 1) {
        rp += __shfl_down(rp, off);
        rn += __shfl_down(rn, off);
    }
    if (lane == 0) {
        atomicAdd(&acc[cur * 2 + 0], rp);
        atomicAdd(&acc[cur * 2 + 1], rn);
    }
}

// Single tiny kernel: out = sum_b min(loss_pos[b], loss_neg[b])
__global__ void umse_final(const float* __restrict__ acc, float* __restrict__ out) {
    if (threadIdx.x == 0 && blockIdx.x == 0) {
        float s = 0.f;
        #pragma unroll
        for (int b = 0; b < B_SEG; ++b) {
            s += fminf(acc[2 * b + 0], acc[2 * b + 1]);
        }
        out[0] = s;
    }
}

extern "C" void kernel_launch(void* const* d_in, const int* in_sizes, int n_in,
                              void* d_out, int out_size, void* d_ws, size_t ws_size,
                              hipStream_t stream) {
    const float* input  = (const float*)d_in[0];
    const float* target = (const float*)d_in[1];
    const int*   batch  = (const int*)d_in[2];
    float* acc = (float*)d_ws;

    // zero the B_SEG*2 accumulators every call (d_ws is not re-poisoned between replays)
    hipMemsetAsync(acc, 0, B_SEG * 2 * sizeof(float), stream);

    const int waves  = N_ROWS / ROWS_PER_WAVE;      // 8192
    const int blocks = waves * 64 / 256;            // 2048 blocks, 256 thr
    umse_main<<<blocks, 256, 0, stream>>>(input, target, batch, acc);
    umse_final<<<1, 64, 0, stream>>>(acc, (float*)d_out);
}